// Round 2
// baseline (1293.403 us; speedup 1.0000x reference)
//
#include <hip/hip_runtime.h>
#include <hip/hip_bf16.h>

#define E_ 8
#define H_ 2048
#define I_ 1408
#define S_ 2048       // B*S tokens
#define NPAIR 4096    // S_*K
#define MAXMT 32      // worst-case M-tiles per expert (4096/128)

typedef short bf16x8 __attribute__((ext_vector_type(8)));   // 8 bf16 bit-patterns (4 VGPRs)
typedef float f32x4  __attribute__((ext_vector_type(4)));   // MFMA accumulator

// pack 8 fp32 -> 8 bf16 (RNE) as a bf16x8
__device__ inline bf16x8 pack8(float4 a, float4 b) {
    bf16x8 r;
    const float v[8] = {a.x, a.y, a.z, a.w, b.x, b.y, b.z, b.w};
#pragma unroll
    for (int j = 0; j < 8; ++j) {
        __hip_bfloat16 t = __float2bfloat16(v[j]);
        r[j] = *reinterpret_cast<short*>(&t);
    }
    return r;
}

// ---------------------------------------------------------------- router ----
__global__ void moe_router(const int* __restrict__ idx,
                           const float* __restrict__ wts,
                           int* __restrict__ counts, int* __restrict__ bases,
                           int* __restrict__ tok, float* __restrict__ wgt) {
    __shared__ int cnt[E_];
    __shared__ int cur[E_];
    const int tid = threadIdx.x;
    if (tid < E_) cnt[tid] = 0;
    __syncthreads();
    for (int p = tid; p < NPAIR; p += 256)
        atomicAdd(&cnt[idx[p]], 1);
    __syncthreads();
    if (tid == 0) {
        int b = 0;
        for (int e = 0; e < E_; ++e) {
            counts[e] = cnt[e];
            bases[e]  = b;
            cur[e]    = b;
            b += cnt[e];
        }
    }
    __syncthreads();
    for (int p = tid; p < NPAIR; p += 256) {
        const int e = idx[p];
        const int pos = atomicAdd(&cur[e], 1);
        tok[pos] = p >> 1;            // token id (K=2)
        wgt[pos] = wts[p];            // pair weight (fp32)
    }
}

// -------------------------------------------------------------- zero out ----
__global__ void zero_out(float* __restrict__ a) {
    const size_t i = ((size_t)blockIdx.x * 256 + threadIdx.x) * 4;
    *(float4*)(a + i) = make_float4(0.f, 0.f, 0.f, 0.f);
}

// ----------------------------------------------------------------- GEMM1 ----
// X_gathered(count x 2048) @ gate_up[e]^T (fp32 weights -> bf16 staged),
// fused SiLU(gate)*up -> h (bf16) in ws
__global__ void moe_gemm1(const float* __restrict__ x,
                          const float* __restrict__ wg,
                          const int* __restrict__ counts,
                          const int* __restrict__ bases,
                          const int* __restrict__ tok,
                          ushort* __restrict__ hbuf) {
    const int e  = blockIdx.y / MAXMT;
    const int mt = blockIdx.y % MAXMT;
    const int count = counts[e];
    if (mt * 128 >= count) return;
    const int base = bases[e];
    const int n0 = blockIdx.x * 128;
    const float* wge = wg + (size_t)e * (2 * I_) * H_;

    __shared__ alignas(16) ushort As[128 * 40];
    __shared__ alignas(16) ushort Bg[128 * 40];
    __shared__ alignas(16) ushort Bu[128 * 40];

    const int tid  = threadIdx.x;
    const int lane = tid & 63;
    const int wid  = tid >> 6;
    const int wm = wid & 1, wn = wid >> 1;
    const int lr = lane & 15, lq = lane >> 4;

    const f32x4 vzero = {0.f, 0.f, 0.f, 0.f};
    f32x4 accg[4][4], accu[4][4];
#pragma unroll
    for (int mi = 0; mi < 4; ++mi)
#pragma unroll
        for (int ni = 0; ni < 4; ++ni) { accg[mi][ni] = vzero; accu[mi][ni] = vzero; }

    const int srow = tid >> 2;          // 0..63
    const int sc8  = (tid & 3) * 8;     // 0,8,16,24

    // hoist the two gathered-row lookups (rr=0,1)
    int trow[2]; bool tvalid[2];
#pragma unroll
    for (int rr = 0; rr < 2; ++rr) {
        const int i = mt * 128 + srow + rr * 64;
        tvalid[rr] = (i < count);
        trow[rr] = tvalid[rr] ? tok[base + i] : 0;
    }

    for (int kt = 0; kt < H_ / 32; ++kt) {
        const int k0 = kt * 32;
        __syncthreads();
#pragma unroll
        for (int rr = 0; rr < 2; ++rr) {
            const int r = srow + rr * 64;
            float4 a0 = make_float4(0.f, 0.f, 0.f, 0.f), a1 = a0;
            if (tvalid[rr]) {
                const float* src = x + (size_t)trow[rr] * H_ + k0 + sc8;
                a0 = *(const float4*)(src);
                a1 = *(const float4*)(src + 4);
            }
            *(bf16x8*)&As[r * 40 + sc8] = pack8(a0, a1);
            const float* gs = wge + (size_t)(n0 + r) * H_ + k0 + sc8;
            *(bf16x8*)&Bg[r * 40 + sc8] = pack8(*(const float4*)gs, *(const float4*)(gs + 4));
            const float* us = wge + (size_t)(I_ + n0 + r) * H_ + k0 + sc8;
            *(bf16x8*)&Bu[r * 40 + sc8] = pack8(*(const float4*)us, *(const float4*)(us + 4));
        }
        __syncthreads();

        bf16x8 a[4], bg[4], bu[4];
#pragma unroll
        for (int mi = 0; mi < 4; ++mi)
            a[mi] = *(const bf16x8*)&As[(wm * 64 + mi * 16 + lr) * 40 + lq * 8];
#pragma unroll
        for (int ni = 0; ni < 4; ++ni) {
            bg[ni] = *(const bf16x8*)&Bg[(wn * 64 + ni * 16 + lr) * 40 + lq * 8];
            bu[ni] = *(const bf16x8*)&Bu[(wn * 64 + ni * 16 + lr) * 40 + lq * 8];
        }
#pragma unroll
        for (int mi = 0; mi < 4; ++mi)
#pragma unroll
            for (int ni = 0; ni < 4; ++ni) {
                accg[mi][ni] = __builtin_amdgcn_mfma_f32_16x16x32_bf16(a[mi], bg[ni], accg[mi][ni], 0, 0, 0);
                accu[mi][ni] = __builtin_amdgcn_mfma_f32_16x16x32_bf16(a[mi], bu[ni], accu[mi][ni], 0, 0, 0);
            }
    }

    // epilogue: h = silu(gate)*up, bf16 store to ws
#pragma unroll
    for (int mi = 0; mi < 4; ++mi) {
#pragma unroll
        for (int r = 0; r < 4; ++r) {
            const int i = mt * 128 + wm * 64 + mi * 16 + lq * 4 + r;
            if (i < count) {
#pragma unroll
                for (int ni = 0; ni < 4; ++ni) {
                    const int col = n0 + wn * 64 + ni * 16 + lr;
                    const float g = accg[mi][ni][r];
                    const float u = accu[mi][ni][r];
                    const float h = (g / (1.0f + __expf(-g))) * u;
                    __hip_bfloat16 hb = __float2bfloat16(h);
                    hbuf[(size_t)(base + i) * I_ + col] = *reinterpret_cast<ushort*>(&hb);
                }
            }
        }
    }
}

// ----------------------------------------------------------------- GEMM2 ----
// h(count x 1408, bf16) @ down[e]^T (fp32 -> bf16 staged), scaled by pair
// weight, atomic fp32 accumulate into d_out
__global__ void moe_gemm2(const ushort* __restrict__ h,
                          const float* __restrict__ wd,
                          const int* __restrict__ counts,
                          const int* __restrict__ bases,
                          const int* __restrict__ tok,
                          const float* __restrict__ wgt,
                          float* __restrict__ out) {
    const int e  = blockIdx.y / MAXMT;
    const int mt = blockIdx.y % MAXMT;
    const int count = counts[e];
    if (mt * 128 >= count) return;
    const int base = bases[e];
    const int n0 = blockIdx.x * 128;
    const float* wde = wd + (size_t)e * H_ * I_;

    __shared__ alignas(16) ushort As[128 * 40];
    __shared__ alignas(16) ushort Bs[128 * 40];

    const int tid  = threadIdx.x;
    const int lane = tid & 63;
    const int wid  = tid >> 6;
    const int wm = wid & 1, wn = wid >> 1;
    const int lr = lane & 15, lq = lane >> 4;

    const f32x4 vzero = {0.f, 0.f, 0.f, 0.f};
    f32x4 acc[4][4];
#pragma unroll
    for (int mi = 0; mi < 4; ++mi)
#pragma unroll
        for (int ni = 0; ni < 4; ++ni) acc[mi][ni] = vzero;

    const int srow = tid >> 2;
    const int sc8  = (tid & 3) * 8;

    for (int kt = 0; kt < I_ / 32; ++kt) {
        const int k0 = kt * 32;
        __syncthreads();
#pragma unroll
        for (int rr = 0; rr < 2; ++rr) {
            const int r = srow + rr * 64;
            uint4 v = {0u, 0u, 0u, 0u};
            const int i = mt * 128 + r;
            if (i < count)
                v = *(const uint4*)(h + (size_t)(base + i) * I_ + k0 + sc8);
            *(uint4*)&As[r * 40 + sc8] = v;
            const float* bs = wde + (size_t)(n0 + r) * I_ + k0 + sc8;
            *(bf16x8*)&Bs[r * 40 + sc8] = pack8(*(const float4*)bs, *(const float4*)(bs + 4));
        }
        __syncthreads();

        bf16x8 a[4], b[4];
#pragma unroll
        for (int mi = 0; mi < 4; ++mi)
            a[mi] = *(const bf16x8*)&As[(wm * 64 + mi * 16 + lr) * 40 + lq * 8];
#pragma unroll
        for (int ni = 0; ni < 4; ++ni)
            b[ni] = *(const bf16x8*)&Bs[(wn * 64 + ni * 16 + lr) * 40 + lq * 8];
#pragma unroll
        for (int mi = 0; mi < 4; ++mi)
#pragma unroll
            for (int ni = 0; ni < 4; ++ni)
                acc[mi][ni] = __builtin_amdgcn_mfma_f32_16x16x32_bf16(a[mi], b[ni], acc[mi][ni], 0, 0, 0);
    }

#pragma unroll
    for (int mi = 0; mi < 4; ++mi) {
#pragma unroll
        for (int r = 0; r < 4; ++r) {
            const int i = mt * 128 + wm * 64 + mi * 16 + lq * 4 + r;
            if (i < count) {
                const float w = wgt[base + i];
                const int   t = tok[base + i];
#pragma unroll
                for (int ni = 0; ni < 4; ++ni) {
                    const int col = n0 + wn * 64 + ni * 16 + lr;
                    unsafeAtomicAdd(&out[(size_t)t * H_ + col], acc[mi][ni][r] * w);
                }
            }
        }
    }
}

// ---------------------------------------------------------------- launch ----
extern "C" void kernel_launch(void* const* d_in, const int* in_sizes, int n_in,
                              void* d_out, int out_size, void* d_ws, size_t ws_size,
                              hipStream_t stream) {
    const float* x   = (const float*)d_in[0];   // hidden_states fp32
    const int*   tki = (const int*)d_in[1];     // top_k_index i32
    const float* tkw = (const float*)d_in[2];   // top_k_weights fp32
    const float* wg  = (const float*)d_in[3];   // gate_up_proj fp32
    const float* wd  = (const float*)d_in[4];   // down_proj fp32
    float* out = (float*)d_out;                 // fp32 output

    // workspace layout
    char* p = (char*)d_ws;
    int* counts = (int*)p;  p += 32;
    int* bases  = (int*)p;  p += 32;
    int* tok    = (int*)p;  p += NPAIR * sizeof(int);
    float* wgt  = (float*)p; p += NPAIR * sizeof(float);
    ushort* hbuf = (ushort*)p;                  // 4096*1408*2 = 11.5 MB

    zero_out<<<dim3((S_ * H_) / (256 * 4)), 256, 0, stream>>>(out);
    moe_router<<<dim3(1), 256, 0, stream>>>(tki, tkw, counts, bases, tok, wgt);
    moe_gemm1<<<dim3(I_ / 128, E_ * MAXMT), 256, 0, stream>>>(x, wg, counts, bases, tok, hbuf);
    moe_gemm2<<<dim3(H_ / 128, E_ * MAXMT), 256, 0, stream>>>(hbuf, wd, counts, bases, tok, wgt, out);
}

// Round 3
// 426.274 us; speedup vs baseline: 3.0342x; 3.0342x over previous
//
#include <hip/hip_runtime.h>
#include <hip/hip_bf16.h>

#define E_ 8
#define H_ 2048
#define I_ 1408
#define S_ 2048       // B*S tokens
#define NPAIR 4096    // S_*K
#define MAXMT 32      // worst-case M-tiles per expert (4096/128)

typedef short bf16x8 __attribute__((ext_vector_type(8)));
typedef ushort u16x8 __attribute__((ext_vector_type(8)));
typedef float f32x4  __attribute__((ext_vector_type(4)));

__device__ inline bf16x8 pack8(float4 a, float4 b) {
    bf16x8 r;
    const float v[8] = {a.x, a.y, a.z, a.w, b.x, b.y, b.z, b.w};
#pragma unroll
    for (int j = 0; j < 8; ++j) {
        __hip_bfloat16 t = __float2bfloat16(v[j]);
        r[j] = *reinterpret_cast<short*>(&t);
    }
    return r;
}

// ---------------------------------------------------------------- router ----
__global__ void moe_router(const int* __restrict__ idx,
                           int* __restrict__ counts, int* __restrict__ bases,
                           int* __restrict__ tok, int* __restrict__ inv) {
    __shared__ int cnt[E_];
    __shared__ int cur[E_];
    const int tid = threadIdx.x;
    if (tid < E_) cnt[tid] = 0;
    __syncthreads();
    for (int p = tid; p < NPAIR; p += 256)
        atomicAdd(&cnt[idx[p]], 1);
    __syncthreads();
    if (tid == 0) {
        int b = 0;
        for (int e = 0; e < E_; ++e) {
            counts[e] = cnt[e];
            bases[e]  = b;
            cur[e]    = b;
            b += cnt[e];
        }
    }
    __syncthreads();
    for (int p = tid; p < NPAIR; p += 256) {
        const int e = idx[p];
        const int pos = atomicAdd(&cur[e], 1);
        tok[pos] = p >> 1;   // token id (K=2)
        inv[p]   = pos;      // pair -> sorted position
    }
}

// ------------------------------------------------------------- convert x ----
__global__ void convert_x(const float* __restrict__ x, ushort* __restrict__ xb) {
    const size_t i = ((size_t)blockIdx.x * 256 + threadIdx.x) * 8;
    const float4 a = *(const float4*)(x + i);
    const float4 b = *(const float4*)(x + i + 4);
    *(bf16x8*)(xb + i) = pack8(a, b);
}

// ----------------------------------------------------------------- GEMM1 ----
// X_gathered(count x 2048, bf16) @ gate_up[e]^T (fp32 cvt-staged),
// fused SiLU(gate)*up -> h bf16, coalesced via LDS transpose.
__global__ __launch_bounds__(256, 2)
void moe_gemm1(const ushort* __restrict__ xb,
               const float* __restrict__ wg,
               const int* __restrict__ counts,
               const int* __restrict__ bases,
               const int* __restrict__ tok,
               ushort* __restrict__ hbuf) {
    const int e  = blockIdx.y & (E_ - 1);
    const int mt = blockIdx.y >> 3;          // mt-major: B-sharing blocks 88 ids apart (same XCD)
    const int count = counts[e];
    if (mt * 128 >= count) return;
    const int base = bases[e];
    const int n0 = blockIdx.x * 128;
    const float* wge = wg + (size_t)e * (2 * I_) * H_;

    __shared__ alignas(16) ushort sm[2][3][5120];   // 60 KB: [buf][A,Bg,Bu][128*40]

    const int tid  = threadIdx.x;
    const int lane = tid & 63;
    const int wid  = tid >> 6;
    const int wm = wid & 1, wn = wid >> 1;
    const int lr = lane & 15, lq = lane >> 4;

    const f32x4 vzero = {0.f, 0.f, 0.f, 0.f};
    f32x4 accg[4][4], accu[4][4];
#pragma unroll
    for (int mi = 0; mi < 4; ++mi)
#pragma unroll
        for (int ni = 0; ni < 4; ++ni) { accg[mi][ni] = vzero; accu[mi][ni] = vzero; }

    const int srow = tid >> 2;          // 0..63
    const int sc8  = (tid & 3) * 8;     // 0,8,16,24
    const int r0 = srow, r1 = srow + 64;

    const int ia0 = mt * 128 + r0, ia1 = mt * 128 + r1;
    const bool v0 = ia0 < count, v1 = ia1 < count;
    const ushort* ap0 = xb + (size_t)(v0 ? tok[base + ia0] : 0) * H_ + sc8;
    const ushort* ap1 = xb + (size_t)(v1 ? tok[base + ia1] : 0) * H_ + sc8;
    const float* gp0 = wge + (size_t)(n0 + r0) * H_ + sc8;
    const float* gp1 = wge + (size_t)(n0 + r1) * H_ + sc8;
    const float* up0 = gp0 + (size_t)I_ * H_;
    const float* up1 = gp1 + (size_t)I_ * H_;

    const uint4 z4 = {0u, 0u, 0u, 0u};
    uint4 ra0, ra1;
    float4 rg0a, rg0b, rg1a, rg1b, ru0a, ru0b, ru1a, ru1b;

    // prologue: k-chunk 0 into regs
    ra0 = v0 ? *(const uint4*)ap0 : z4;
    ra1 = v1 ? *(const uint4*)ap1 : z4;
    rg0a = *(const float4*)gp0; rg0b = *(const float4*)(gp0 + 4);
    rg1a = *(const float4*)gp1; rg1b = *(const float4*)(gp1 + 4);
    ru0a = *(const float4*)up0; ru0b = *(const float4*)(up0 + 4);
    ru1a = *(const float4*)up1; ru1b = *(const float4*)(up1 + 4);
    {
        ushort* As = &sm[0][0][0]; ushort* Bg = &sm[0][1][0]; ushort* Bu = &sm[0][2][0];
        *(uint4*)&As[r0 * 40 + sc8] = ra0;
        *(uint4*)&As[r1 * 40 + sc8] = ra1;
        *(bf16x8*)&Bg[r0 * 40 + sc8] = pack8(rg0a, rg0b);
        *(bf16x8*)&Bg[r1 * 40 + sc8] = pack8(rg1a, rg1b);
        *(bf16x8*)&Bu[r0 * 40 + sc8] = pack8(ru0a, ru0b);
        *(bf16x8*)&Bu[r1 * 40 + sc8] = pack8(ru1a, ru1b);
    }
    __syncthreads();

    for (int kt = 0; kt < H_ / 32; ++kt) {
        const int cur = kt & 1;
        if (kt < H_ / 32 - 1) {     // issue prefetch for k+1 before MFMAs
            ap0 += 32; ap1 += 32; gp0 += 32; gp1 += 32; up0 += 32; up1 += 32;
            ra0 = v0 ? *(const uint4*)ap0 : z4;
            ra1 = v1 ? *(const uint4*)ap1 : z4;
            rg0a = *(const float4*)gp0; rg0b = *(const float4*)(gp0 + 4);
            rg1a = *(const float4*)gp1; rg1b = *(const float4*)(gp1 + 4);
            ru0a = *(const float4*)up0; ru0b = *(const float4*)(up0 + 4);
            ru1a = *(const float4*)up1; ru1b = *(const float4*)(up1 + 4);
        }
        const ushort* As = &sm[cur][0][0];
        const ushort* Bg = &sm[cur][1][0];
        const ushort* Bu = &sm[cur][2][0];
        bf16x8 a[4], bg[4], bu[4];
#pragma unroll
        for (int mi = 0; mi < 4; ++mi)
            a[mi] = *(const bf16x8*)&As[(wm * 64 + mi * 16 + lr) * 40 + lq * 8];
#pragma unroll
        for (int ni = 0; ni < 4; ++ni) {
            bg[ni] = *(const bf16x8*)&Bg[(wn * 64 + ni * 16 + lr) * 40 + lq * 8];
            bu[ni] = *(const bf16x8*)&Bu[(wn * 64 + ni * 16 + lr) * 40 + lq * 8];
        }
#pragma unroll
        for (int mi = 0; mi < 4; ++mi)
#pragma unroll
            for (int ni = 0; ni < 4; ++ni) {
                accg[mi][ni] = __builtin_amdgcn_mfma_f32_16x16x32_bf16(a[mi], bg[ni], accg[mi][ni], 0, 0, 0);
                accu[mi][ni] = __builtin_amdgcn_mfma_f32_16x16x32_bf16(a[mi], bu[ni], accu[mi][ni], 0, 0, 0);
            }
        if (kt < H_ / 32 - 1) {
            ushort* nA = &sm[cur ^ 1][0][0];
            ushort* nG = &sm[cur ^ 1][1][0];
            ushort* nU = &sm[cur ^ 1][2][0];
            *(uint4*)&nA[r0 * 40 + sc8] = ra0;
            *(uint4*)&nA[r1 * 40 + sc8] = ra1;
            *(bf16x8*)&nG[r0 * 40 + sc8] = pack8(rg0a, rg0b);
            *(bf16x8*)&nG[r1 * 40 + sc8] = pack8(rg1a, rg1b);
            *(bf16x8*)&nU[r0 * 40 + sc8] = pack8(ru0a, ru0b);
            *(bf16x8*)&nU[r1 * 40 + sc8] = pack8(ru1a, ru1b);
        }
        __syncthreads();
    }

    // epilogue: silu(g)*u -> bf16 tile in LDS (stride 136) -> coalesced stores
    ushort* Ht = &sm[0][0][0];     // 128*136 ushorts = 34 KB, fits in 60 KB
#pragma unroll
    for (int mi = 0; mi < 4; ++mi)
#pragma unroll
        for (int r = 0; r < 4; ++r) {
            const int row = wm * 64 + mi * 16 + lq * 4 + r;
#pragma unroll
            for (int ni = 0; ni < 4; ++ni) {
                const int col = wn * 64 + ni * 16 + lr;
                const float g = accg[mi][ni][r];
                const float u = accu[mi][ni][r];
                const float h = (g / (1.0f + __expf(-g))) * u;
                __hip_bfloat16 hb = __float2bfloat16(h);
                Ht[row * 136 + col] = *reinterpret_cast<ushort*>(&hb);
            }
        }
    __syncthreads();
#pragma unroll
    for (int p = 0; p < 8; ++p) {
        const int slot = p * 256 + tid;
        const int row = slot >> 4;
        const int cc  = (slot & 15) * 8;
        const int gi = mt * 128 + row;
        if (gi < count)
            *(uint4*)&hbuf[(size_t)(base + gi) * I_ + n0 + cc] = *(const uint4*)&Ht[row * 136 + cc];
    }
}

// ----------------------------------------------------------------- GEMM2 ----
// h(count x 1408, bf16) @ down[e]^T (fp32 cvt-staged) -> per-pair y bf16
__global__ __launch_bounds__(256, 2)
void moe_gemm2(const ushort* __restrict__ hbuf,
               const float* __restrict__ wd,
               const int* __restrict__ counts,
               const int* __restrict__ bases,
               ushort* __restrict__ ybuf) {
    const int e  = blockIdx.y & (E_ - 1);
    const int mt = blockIdx.y >> 3;
    const int count = counts[e];
    if (mt * 128 >= count) return;
    const int base = bases[e];
    const int n0 = blockIdx.x * 128;
    const float* wde = wd + (size_t)e * H_ * I_;

    __shared__ alignas(16) ushort sm[2][2][5120];   // 40 KB

    const int tid  = threadIdx.x;
    const int lane = tid & 63;
    const int wid  = tid >> 6;
    const int wm = wid & 1, wn = wid >> 1;
    const int lr = lane & 15, lq = lane >> 4;

    const f32x4 vzero = {0.f, 0.f, 0.f, 0.f};
    f32x4 acc[4][4];
#pragma unroll
    for (int mi = 0; mi < 4; ++mi)
#pragma unroll
        for (int ni = 0; ni < 4; ++ni) acc[mi][ni] = vzero;

    const int srow = tid >> 2;
    const int sc8  = (tid & 3) * 8;
    const int r0 = srow, r1 = srow + 64;

    const int ia0 = mt * 128 + r0, ia1 = mt * 128 + r1;
    const bool v0 = ia0 < count, v1 = ia1 < count;
    const ushort* ap0 = hbuf + (size_t)(base + (v0 ? ia0 : 0)) * I_ + sc8;
    const ushort* ap1 = hbuf + (size_t)(base + (v1 ? ia1 : 0)) * I_ + sc8;
    const float* bp0 = wde + (size_t)(n0 + r0) * I_ + sc8;
    const float* bp1 = wde + (size_t)(n0 + r1) * I_ + sc8;

    const uint4 z4 = {0u, 0u, 0u, 0u};
    uint4 ra0, ra1;
    float4 rb0a, rb0b, rb1a, rb1b;

    ra0 = v0 ? *(const uint4*)ap0 : z4;
    ra1 = v1 ? *(const uint4*)ap1 : z4;
    rb0a = *(const float4*)bp0; rb0b = *(const float4*)(bp0 + 4);
    rb1a = *(const float4*)bp1; rb1b = *(const float4*)(bp1 + 4);
    {
        ushort* As = &sm[0][0][0]; ushort* Bs = &sm[0][1][0];
        *(uint4*)&As[r0 * 40 + sc8] = ra0;
        *(uint4*)&As[r1 * 40 + sc8] = ra1;
        *(bf16x8*)&Bs[r0 * 40 + sc8] = pack8(rb0a, rb0b);
        *(bf16x8*)&Bs[r1 * 40 + sc8] = pack8(rb1a, rb1b);
    }
    __syncthreads();

    for (int kt = 0; kt < I_ / 32; ++kt) {
        const int cur = kt & 1;
        if (kt < I_ / 32 - 1) {
            ap0 += 32; ap1 += 32; bp0 += 32; bp1 += 32;
            ra0 = v0 ? *(const uint4*)ap0 : z4;
            ra1 = v1 ? *(const uint4*)ap1 : z4;
            rb0a = *(const float4*)bp0; rb0b = *(const float4*)(bp0 + 4);
            rb1a = *(const float4*)bp1; rb1b = *(const float4*)(bp1 + 4);
        }
        const ushort* As = &sm[cur][0][0];
        const ushort* Bs = &sm[cur][1][0];
        bf16x8 a[4], b[4];
#pragma unroll
        for (int mi = 0; mi < 4; ++mi)
            a[mi] = *(const bf16x8*)&As[(wm * 64 + mi * 16 + lr) * 40 + lq * 8];
#pragma unroll
        for (int ni = 0; ni < 4; ++ni)
            b[ni] = *(const bf16x8*)&Bs[(wn * 64 + ni * 16 + lr) * 40 + lq * 8];
#pragma unroll
        for (int mi = 0; mi < 4; ++mi)
#pragma unroll
            for (int ni = 0; ni < 4; ++ni)
                acc[mi][ni] = __builtin_amdgcn_mfma_f32_16x16x32_bf16(a[mi], b[ni], acc[mi][ni], 0, 0, 0);
        if (kt < I_ / 32 - 1) {
            ushort* nA = &sm[cur ^ 1][0][0];
            ushort* nB = &sm[cur ^ 1][1][0];
            *(uint4*)&nA[r0 * 40 + sc8] = ra0;
            *(uint4*)&nA[r1 * 40 + sc8] = ra1;
            *(bf16x8*)&nB[r0 * 40 + sc8] = pack8(rb0a, rb0b);
            *(bf16x8*)&nB[r1 * 40 + sc8] = pack8(rb1a, rb1b);
        }
        __syncthreads();
    }

    // epilogue: y -> bf16 LDS tile -> coalesced stores to ybuf
    ushort* Yt = &sm[0][0][0];
#pragma unroll
    for (int mi = 0; mi < 4; ++mi)
#pragma unroll
        for (int r = 0; r < 4; ++r) {
            const int row = wm * 64 + mi * 16 + lq * 4 + r;
#pragma unroll
            for (int ni = 0; ni < 4; ++ni) {
                const int col = wn * 64 + ni * 16 + lr;
                __hip_bfloat16 yb = __float2bfloat16(acc[mi][ni][r]);
                Yt[row * 136 + col] = *reinterpret_cast<ushort*>(&yb);
            }
        }
    __syncthreads();
#pragma unroll
    for (int p = 0; p < 8; ++p) {
        const int slot = p * 256 + tid;
        const int row = slot >> 4;
        const int cc  = (slot & 15) * 8;
        const int gi = mt * 128 + row;
        if (gi < count)
            *(uint4*)&ybuf[(size_t)(base + gi) * H_ + n0 + cc] = *(const uint4*)&Yt[row * 136 + cc];
    }
}

// --------------------------------------------------------------- combine ----
// out[t] = w[2t]*y[inv[2t]] + w[2t+1]*y[inv[2t+1]]   (overwrites d_out fully)
__global__ void moe_combine(const ushort* __restrict__ ybuf,
                            const int* __restrict__ inv,
                            const float* __restrict__ tkw,
                            float* __restrict__ out) {
    const int t = blockIdx.x;
    const int c8 = threadIdx.x * 8;
    const int p0 = inv[2 * t], p1 = inv[2 * t + 1];
    const float w0 = tkw[2 * t], w1 = tkw[2 * t + 1];
    const u16x8 y0 = *(const u16x8*)(ybuf + (size_t)p0 * H_ + c8);
    const u16x8 y1 = *(const u16x8*)(ybuf + (size_t)p1 * H_ + c8);
    float o[8];
#pragma unroll
    for (int j = 0; j < 8; ++j) {
        const unsigned f0 = ((unsigned)y0[j]) << 16;
        const unsigned f1 = ((unsigned)y1[j]) << 16;
        o[j] = w0 * __uint_as_float(f0) + w1 * __uint_as_float(f1);
    }
    float* dst = out + (size_t)t * H_ + c8;
    *(float4*)dst       = make_float4(o[0], o[1], o[2], o[3]);
    *(float4*)(dst + 4) = make_float4(o[4], o[5], o[6], o[7]);
}

// ---------------------------------------------------------------- launch ----
extern "C" void kernel_launch(void* const* d_in, const int* in_sizes, int n_in,
                              void* d_out, int out_size, void* d_ws, size_t ws_size,
                              hipStream_t stream) {
    const float* x   = (const float*)d_in[0];
    const int*   tki = (const int*)d_in[1];
    const float* tkw = (const float*)d_in[2];
    const float* wg  = (const float*)d_in[3];
    const float* wd  = (const float*)d_in[4];
    float* out = (float*)d_out;

    // ws layout (all 16B-aligned)
    char* p = (char*)d_ws;
    int* counts = (int*)p;  p += 32;
    int* bases  = (int*)p;  p += 32;
    int* tok    = (int*)p;  p += NPAIR * sizeof(int);
    int* inv    = (int*)p;  p += NPAIR * sizeof(int);
    ushort* xb   = (ushort*)p; p += (size_t)S_ * H_ * 2;       // 8 MB
    ushort* hbuf = (ushort*)p; p += (size_t)NPAIR * I_ * 2;    // 11.5 MB
    ushort* ybuf = (ushort*)p; p += (size_t)NPAIR * H_ * 2;    // 16.8 MB

    convert_x<<<dim3((S_ * H_) / (256 * 8)), 256, 0, stream>>>(x, xb);
    moe_router<<<dim3(1), 256, 0, stream>>>(tki, counts, bases, tok, inv);
    moe_gemm1<<<dim3(I_ / 128, E_ * MAXMT), 256, 0, stream>>>(xb, wg, counts, bases, tok, hbuf);
    moe_gemm2<<<dim3(H_ / 128, E_ * MAXMT), 256, 0, stream>>>(hbuf, wd, counts, bases, ybuf);
    moe_combine<<<dim3(S_), 256, 0, stream>>>(ybuf, inv, tkw, out);
}